// Round 13
// baseline (286.347 us; speedup 1.0000x reference)
//
#include <hip/hip_runtime.h>
#include <cstdint>
#include <cstddef>

#define D_DIM   256
#define B_ROWS  1024
#define C_CLS   200000
#define S_SC    64.0f
#define COS_M_F 0.87758256189037271612f
#define SIN_M_F 0.47942553860420300027f
#define EPS_F   1e-8f

#define CT 256                     /* classes per block (8 waves x 32) */
#define NCB 782                    /* 782*256 = 200192 class tiles = grid */
#define CPAD (NCB * CT)            /* 200192 */
#define NPADROW (CPAD - C_CLS)     /* 192 zero rows -> exp(0)=1 each */

typedef int   i32x4  __attribute__((ext_vector_type(4)));
typedef int   i32x8  __attribute__((ext_vector_type(8)));
typedef float f32x16 __attribute__((ext_vector_type(16)));

// ---------------- kernel 1: normalize {proto, emb} -> fp8 e4m3 ----------------
__global__ void k_norm_all8(const float* __restrict__ emb,
                            const float* __restrict__ proto,
                            unsigned char* __restrict__ ebf8,
                            unsigned char* __restrict__ pbf8) {
  int wid = threadIdx.x >> 6, lane = threadIdx.x & 63;
  int idx = (blockIdx.x << 2) + wid;
  const float* src;
  unsigned char* dst;
  if (idx < CPAD) {
    if (idx >= C_CLS) {
      *reinterpret_cast<unsigned int*>(pbf8 + (size_t)idx * D_DIM + lane * 4) = 0u;
      return;
    }
    src = proto + (size_t)idx * D_DIM;
    dst = pbf8 + (size_t)idx * D_DIM;
  } else {
    int row = idx - CPAD;
    src = emb + (size_t)row * D_DIM;
    dst = ebf8 + (size_t)row * D_DIM;
  }
  const float4 v = *reinterpret_cast<const float4*>(src + lane * 4);
  float ss = v.x * v.x + v.y * v.y + v.z * v.z + v.w * v.w;
#pragma unroll
  for (int m = 32; m >= 1; m >>= 1) ss += __shfl_xor(ss, m, 64);
  float inv = 1.0f / fmaxf(sqrtf(ss), 1e-12f);
  int packed = 0;
  packed = __builtin_amdgcn_cvt_pk_fp8_f32(v.x * inv, v.y * inv, packed, false);
  packed = __builtin_amdgcn_cvt_pk_fp8_f32(v.z * inv, v.w * inv, packed, true);
  *reinterpret_cast<int*>(dst + lane * 4) = packed;
}

// ------- kernel 2: register-resident MX-fp8 GEMM, 8 waves x 32 classes --------
// Wave owns 32 classes x full K=256 in 32 VGPR (af), loaded once and PINNED
// via inline-asm so the compiler cannot rematerialize (R12 lesson: VGPR=56
// meant af was reloaded every strip). Zero LDS / zero barriers in the K-path;
// emb fragments stream global->reg (L1/L2-hot, 16 waves/CU TLP).
__global__ __launch_bounds__(512, 4) void k_gemm_cls(
    const unsigned char* __restrict__ ebf8, const unsigned char* __restrict__ pbf8,
    float* __restrict__ sums) {
  __shared__ float bsum[8][B_ROWS];   // 32 KiB, per-wave private rows

  const int t = threadIdx.x;
  const int lane = t & 63;
  const int rsel = lane & 31;        // class-row (A) / batch-col (B) within 32
  const int h = lane >> 5;           // k-half of each 64-K window
  const int wv = t >> 6;             // wave 0..7

  const int c0 = (int)blockIdx.x * CT + wv * 32;

  // ---- prologue: A (proto) fragments global->reg, 32 VGPR, then pin ----
  i32x8 af[4];
  {
    const unsigned char* ab = pbf8 + (size_t)(c0 + rsel) * D_DIM + h * 32;
#pragma unroll
    for (int ks = 0; ks < 4; ++ks) {
      i32x4 lo = *reinterpret_cast<const i32x4*>(ab + ks * 64);
      i32x4 hi = *reinterpret_cast<const i32x4*>(ab + ks * 64 + 16);
      af[ks] = __builtin_shufflevector(lo, hi, 0, 1, 2, 3, 4, 5, 6, 7);
    }
  }
#pragma unroll
  for (int ks = 0; ks < 4; ++ks)
    asm volatile("" : "+v"(af[ks]));   // anti-remat pin: af stays in VGPRs

  // ---- batch loop: 32 strips of 32 cols; no LDS, no barriers ----
  const unsigned char* ebase = ebf8 + (size_t)rsel * D_DIM + h * 32;
#pragma unroll 1
  for (int s = 0; s < 32; ++s) {
    const unsigned char* eb = ebase + (size_t)s * (32 * D_DIM);
    i32x8 bf[4];
#pragma unroll
    for (int ks = 0; ks < 4; ++ks) {
      i32x4 lo = *reinterpret_cast<const i32x4*>(eb + ks * 64);
      i32x4 hi = *reinterpret_cast<const i32x4*>(eb + ks * 64 + 16);
      bf[ks] = __builtin_shufflevector(lo, hi, 0, 1, 2, 3, 4, 5, 6, 7);
    }
    f32x16 acc;
#pragma unroll
    for (int e = 0; e < 16; ++e) acc[e] = 0.0f;
    __builtin_amdgcn_s_setprio(1);
#pragma unroll
    for (int ks = 0; ks < 4; ++ks)
      acc = __builtin_amdgcn_mfma_scale_f32_32x32x64_f8f6f4(
          af[ks], bf[ks], acc, 0, 0,          // cbsz=fp8, blgp=fp8
          0, 0x7F7F7F7F, 0, 0x7F7F7F7F);      // unit scales (E8M0=127)
    __builtin_amdgcn_s_setprio(0);
    // in-lane exp-sum over this lane's 16 class rows for batch col s*32+rsel
    float bp = 0.0f;
#pragma unroll
    for (int e = 0; e < 16; ++e)
      bp += __expf(S_SC * acc[e]);
    bp += __shfl_xor(bp, 32, 64);    // combine the two k-half lane groups
    if (h == 0) bsum[wv][s * 32 + rsel] = bp;
  }

  // ---- block reduce: 8 wave rows -> global atomic ----
  __syncthreads();
#pragma unroll
  for (int j = 0; j < 2; ++j) {
    int col = t + j * 512;
    float v = bsum[0][col] + bsum[1][col] + bsum[2][col] + bsum[3][col]
            + bsum[4][col] + bsum[5][col] + bsum[6][col] + bsum[7][col];
    atomicAdd(&sums[col], v);
  }
}

// ---------------- kernel 3: label column + final loss -------------------------
__device__ __forceinline__ float f8tof(unsigned char u) {
  int e = (u >> 3) & 15, m = u & 7;
  float mag = e ? ldexpf((float)(8 + m), e - 10) : ldexpf((float)m, -9);
  return (u & 0x80) ? -mag : mag;
}

__global__ void k_finalize(const unsigned char* __restrict__ ebf8,
                           const unsigned char* __restrict__ pbf8,
                           const int* __restrict__ labels,
                           const float* __restrict__ sums,
                           float* __restrict__ out) {
  __shared__ float part[4];
  int wid = threadIdx.x >> 6, lane = threadIdx.x & 63;
  int b = (blockIdx.x << 2) + wid;
  int lab = labels[b];
  const unsigned char* e = ebf8 + (size_t)b * D_DIM + lane * 4;
  const unsigned char* p = pbf8 + (size_t)lab * D_DIM + lane * 4;
  unsigned int eu = *reinterpret_cast<const unsigned int*>(e);
  unsigned int pu = *reinterpret_cast<const unsigned int*>(p);
  float dot = 0.0f;
#pragma unroll
  for (int i = 0; i < 4; ++i)
    dot += f8tof((eu >> (8 * i)) & 0xff) * f8tof((pu >> (8 * i)) & 0xff);
#pragma unroll
  for (int m = 32; m >= 1; m >>= 1) dot += __shfl_xor(dot, m, 64);
  if (lane == 0) {
    float cs = dot;
    float sn = sqrtf(fmaxf(1.0f - cs * cs, EPS_F));
    sn = fminf(fmaxf(sn, EPS_F), 1.0f - EPS_F);
    float phi = cs * COS_M_F - sn * SIN_M_F;
    float sp = S_SC * phi;
    // subtract the 192 zero-pad rows' exp(0)=1 contributions
    float total = sums[b] - (float)NPADROW - __expf(S_SC * cs) + __expf(sp);
    part[wid] = logf(total) - sp;
  }
  __syncthreads();
  if (threadIdx.x == 0) {
    float s = part[0] + part[1] + part[2] + part[3];
    atomicAdd(out, s * (1.0f / (float)B_ROWS));
  }
}

// ---------------- launcher ----------------------------------------------------
extern "C" void kernel_launch(void* const* d_in, const int* in_sizes, int n_in,
                              void* d_out, int out_size, void* d_ws, size_t ws_size,
                              hipStream_t stream) {
  const float* emb    = (const float*)d_in[0];
  const int*   labels = (const int*)d_in[1];
  const float* proto  = (const float*)d_in[2];
  float* out = (float*)d_out;

  char* ws = (char*)d_ws;
  unsigned char* ebf8 = (unsigned char*)ws;                 // 262144 B
  float* sums = (float*)(ws + 262144);                      // 4096 B
  unsigned char* pbf8 = (unsigned char*)(ws + 2097152);     // CPAD*256 = 51.2 MB

  hipMemsetAsync(sums, 0, B_ROWS * sizeof(float), stream);
  hipMemsetAsync(out, 0, sizeof(float), stream);

  k_norm_all8<<<(CPAD + B_ROWS) / 4, 256, 0, stream>>>(emb, proto, ebf8, pbf8);
  k_gemm_cls<<<NCB, 512, 0, stream>>>(ebf8, pbf8, sums);
  k_finalize<<<B_ROWS / 4, 256, 0, stream>>>(ebf8, pbf8, labels, sums, out);
}

// Round 14
// 280.617 us; speedup vs baseline: 1.0204x; 1.0204x over previous
//
#include <hip/hip_runtime.h>
#include <cstdint>
#include <cstddef>

#define D_DIM   256
#define B_ROWS  1024
#define C_CLS   200000
#define S_SC    64.0f
#define COS_M_F 0.87758256189037271612f
#define SIN_M_F 0.47942553860420300027f
#define EPS_F   1e-8f

#define CT 256                     /* classes per block */
#define NCB 782                    /* grid: 782*256 = 200192 >= 200000 */
#define CPAD (NCB * CT)
#define NPADROW (CPAD - C_CLS)     /* 192 zero rows -> exp(0)=1 each */

typedef int   i32x4  __attribute__((ext_vector_type(4)));
typedef int   i32x8  __attribute__((ext_vector_type(8)));
typedef float f32x16 __attribute__((ext_vector_type(16)));

// ---------------- kernel 1: normalize embeddings -> fp8 e4m3 ------------------
__global__ void k_norm_emb8(const float* __restrict__ emb,
                            unsigned char* __restrict__ ebf8) {
  int wid = threadIdx.x >> 6, lane = threadIdx.x & 63;
  int row = (blockIdx.x << 2) + wid;
  const float4 v = *reinterpret_cast<const float4*>(emb + (size_t)row * D_DIM + lane * 4);
  float ss = v.x * v.x + v.y * v.y + v.z * v.z + v.w * v.w;
#pragma unroll
  for (int m = 32; m >= 1; m >>= 1) ss += __shfl_xor(ss, m, 64);
  float inv = 1.0f / fmaxf(sqrtf(ss), 1e-12f);
  int packed = 0;
  packed = __builtin_amdgcn_cvt_pk_fp8_f32(v.x * inv, v.y * inv, packed, false);
  packed = __builtin_amdgcn_cvt_pk_fp8_f32(v.z * inv, v.w * inv, packed, true);
  *reinterpret_cast<int*>(ebf8 + (size_t)row * D_DIM + lane * 4) = packed;
}

// ------- kernel 2: FUSED proto-norm + MX-fp8 GEMM + in-lane exp-sum -----------
// Block owns 256 classes. Prologue: read proto fp32 (the mandatory HBM pass),
// normalize in-register, cvt -> fp8 A-tile in LDS (64 KB, staged ONCE for all
// 1024 batch cols). Loop over 32 batch strips: emb frags global->reg (L2-hot),
// af from LDS, 4 chained mfma_scale 32x32x64, in-lane exp-sum. No pbf8 buffer,
// no separate proto pass, barrier-free K/batch path.
__global__ __launch_bounds__(512, 4) void k_gemm_fused(
    const float* __restrict__ proto, const unsigned char* __restrict__ ebf8,
    float* __restrict__ sums) {
  __shared__ __align__(16) unsigned char Pls[CT * 256];   // 64 KiB, row = 256 B
  __shared__ float bsum[B_ROWS];                          // 4 KiB

  const int t = threadIdx.x;
  const int lane = t & 63;
  const int rsel = lane & 31;        // class-row (A) / batch-col (B) within 32
  const int h = lane >> 5;           // k-half of each 64-K window
  const int wv = t >> 6;             // wave 0..7
  const int c0 = (int)blockIdx.x * CT;

  bsum[t] = 0.0f;
  bsum[t + 512] = 0.0f;

  // ---- prologue: 2 passes x 128 rows; 4 threads/row, 64 floats each ----
#pragma unroll
  for (int pass = 0; pass < 2; ++pass) {
    const int r = pass * 128 + (t >> 2);   // row within tile
    const int q = t & 3;                   // 64-float quarter
    const int row = c0 + r;
    float4 v[16];
    float ss = 0.0f;
    if (row < C_CLS) {
      const float4* src =
          reinterpret_cast<const float4*>(proto + (size_t)row * D_DIM + q * 64);
#pragma unroll
      for (int i = 0; i < 16; ++i) {
        v[i] = src[i];
        ss += v[i].x * v[i].x + v[i].y * v[i].y + v[i].z * v[i].z + v[i].w * v[i].w;
      }
    } else {
#pragma unroll
      for (int i = 0; i < 16; ++i) v[i] = (float4){0.f, 0.f, 0.f, 0.f};
    }
    ss += __shfl_xor(ss, 1, 64);
    ss += __shfl_xor(ss, 2, 64);
    float inv = 1.0f / fmaxf(sqrtf(ss), 1e-12f);
    // cvt 64 floats -> 4 x 16-B granules; logical granule lg = q*4+j,
    // phys = lg ^ (r & 15) (same swizzle family as R8/R11-verified reads)
#pragma unroll
    for (int j = 0; j < 4; ++j) {
      i32x4 w;
#pragma unroll
      for (int u = 0; u < 4; ++u) {
        const float4 a = v[j * 4 + u];
        int pk = 0;
        pk = __builtin_amdgcn_cvt_pk_fp8_f32(a.x * inv, a.y * inv, pk, false);
        pk = __builtin_amdgcn_cvt_pk_fp8_f32(a.z * inv, a.w * inv, pk, true);
        w[u] = pk;
      }
      int lg = q * 4 + j;
      int phys = lg ^ (r & 15);
      *reinterpret_cast<i32x4*>(Pls + r * 256 + phys * 16) = w;
    }
  }
  __syncthreads();                   // ONLY barrier before the epilogue

  // ---- batch loop: 32 strips of 32 cols; no barriers ----
  const unsigned char* ebase = ebf8 + (size_t)rsel * D_DIM + h * 32;
  const int ra = wv * 32 + rsel;     // this lane's A row
#pragma unroll 1
  for (int s = 0; s < 32; ++s) {
    const unsigned char* eb = ebase + (size_t)s * (32 * D_DIM);
    i32x8 bf[4];
#pragma unroll
    for (int ks = 0; ks < 4; ++ks) {
      i32x4 lo = *reinterpret_cast<const i32x4*>(eb + ks * 64);
      i32x4 hi = *reinterpret_cast<const i32x4*>(eb + ks * 64 + 16);
      bf[ks] = __builtin_shufflevector(lo, hi, 0, 1, 2, 3, 4, 5, 6, 7);
    }
    f32x16 acc;
#pragma unroll
    for (int e = 0; e < 16; ++e) acc[e] = 0.0f;
#pragma unroll
    for (int ks = 0; ks < 4; ++ks) {
      int g = ks * 4 + h * 2;
      int p0 = g ^ (ra & 15), p1 = (g + 1) ^ (ra & 15);
      i32x4 lo = *reinterpret_cast<const i32x4*>(Pls + ra * 256 + p0 * 16);
      i32x4 hi = *reinterpret_cast<const i32x4*>(Pls + ra * 256 + p1 * 16);
      i32x8 af = __builtin_shufflevector(lo, hi, 0, 1, 2, 3, 4, 5, 6, 7);
      acc = __builtin_amdgcn_mfma_scale_f32_32x32x64_f8f6f4(
          af, bf[ks], acc, 0, 0,            // cbsz=fp8, blgp=fp8
          0, 0x7F7F7F7F, 0, 0x7F7F7F7F);    // unit scales (E8M0=127)
    }
    // in-lane exp-sum over this lane's 16 class rows for batch col s*32+rsel
    float bp = 0.0f;
#pragma unroll
    for (int e = 0; e < 16; ++e)
      bp += __expf(S_SC * acc[e]);
    bp += __shfl_xor(bp, 32, 64);    // combine the two k-half lane groups
    if (h == 0) atomicAdd(&bsum[s * 32 + rsel], bp);
  }

  // ---- block reduce -> global ----
  __syncthreads();
  atomicAdd(&sums[t], bsum[t]);
  atomicAdd(&sums[t + 512], bsum[t + 512]);
}

// ---------------- kernel 3: label column + final loss -------------------------
__device__ __forceinline__ float f8tof(unsigned char u) {
  int e = (u >> 3) & 15, m = u & 7;
  float mag = e ? ldexpf((float)(8 + m), e - 10) : ldexpf((float)m, -9);
  return (u & 0x80) ? -mag : mag;
}

__global__ void k_finalize(const unsigned char* __restrict__ ebf8,
                           const float* __restrict__ proto,
                           const int* __restrict__ labels,
                           const float* __restrict__ sums,
                           float* __restrict__ out) {
  __shared__ float part[4];
  int wid = threadIdx.x >> 6, lane = threadIdx.x & 63;
  int b = (blockIdx.x << 2) + wid;
  int lab = labels[b];
  // quantize the label prototype row exactly like the GEMM prologue (cvt_pk)
  const float4 pv =
      reinterpret_cast<const float4*>(proto + (size_t)lab * D_DIM)[lane];
  float ss = pv.x * pv.x + pv.y * pv.y + pv.z * pv.z + pv.w * pv.w;
#pragma unroll
  for (int m = 32; m >= 1; m >>= 1) ss += __shfl_xor(ss, m, 64);
  float inv = 1.0f / fmaxf(sqrtf(ss), 1e-12f);
  int pk = 0;
  pk = __builtin_amdgcn_cvt_pk_fp8_f32(pv.x * inv, pv.y * inv, pk, false);
  pk = __builtin_amdgcn_cvt_pk_fp8_f32(pv.z * inv, pv.w * inv, pk, true);
  unsigned int pu = (unsigned int)pk;
  unsigned int eu =
      *reinterpret_cast<const unsigned int*>(ebf8 + (size_t)b * D_DIM + lane * 4);
  float dot = 0.0f;
#pragma unroll
  for (int i = 0; i < 4; ++i)
    dot += f8tof((eu >> (8 * i)) & 0xff) * f8tof((pu >> (8 * i)) & 0xff);
#pragma unroll
  for (int m = 32; m >= 1; m >>= 1) dot += __shfl_xor(dot, m, 64);
  if (lane == 0) {
    float cs = dot;
    float sn = sqrtf(fmaxf(1.0f - cs * cs, EPS_F));
    sn = fminf(fmaxf(sn, EPS_F), 1.0f - EPS_F);
    float phi = cs * COS_M_F - sn * SIN_M_F;
    float sp = S_SC * phi;
    // subtract the 192 zero-pad rows' exp(0)=1 contributions
    float total = sums[b] - (float)NPADROW - __expf(S_SC * cs) + __expf(sp);
    part[wid] = logf(total) - sp;
  }
  __syncthreads();
  if (threadIdx.x == 0) {
    float s = part[0] + part[1] + part[2] + part[3];
    atomicAdd(out, s * (1.0f / (float)B_ROWS));
  }
}

// ---------------- launcher ----------------------------------------------------
extern "C" void kernel_launch(void* const* d_in, const int* in_sizes, int n_in,
                              void* d_out, int out_size, void* d_ws, size_t ws_size,
                              hipStream_t stream) {
  const float* emb    = (const float*)d_in[0];
  const int*   labels = (const int*)d_in[1];
  const float* proto  = (const float*)d_in[2];
  float* out = (float*)d_out;

  char* ws = (char*)d_ws;
  unsigned char* ebf8 = (unsigned char*)ws;        // 262144 B
  float* sums = (float*)(ws + 262144);             // 4096 B

  hipMemsetAsync(sums, 0, B_ROWS * sizeof(float), stream);
  hipMemsetAsync(out, 0, sizeof(float), stream);

  k_norm_emb8<<<B_ROWS / 4, 256, 0, stream>>>(emb, ebf8);
  k_gemm_fused<<<NCB, 512, 0, stream>>>(proto, ebf8, sums);
  k_finalize<<<B_ROWS / 4, 256, 0, stream>>>(ebf8, proto, labels, sums, out);
}

// Round 15
// 152.374 us; speedup vs baseline: 1.8792x; 1.8416x over previous
//
#include <hip/hip_runtime.h>
#include <cstdint>
#include <cstddef>

#define D_DIM   256
#define B_ROWS  1024
#define C_CLS   200000
#define S_SC    64.0f
#define COS_M_F 0.87758256189037271612f
#define SIN_M_F 0.47942553860420300027f
#define EPS_F   1e-8f

#define CT 256                     /* classes per block */
#define NCT 782                    /* 782*256 = 200192 class tiles */
#define CPAD (NCT * CT)            /* 200192 */
#define NPADROW (CPAD - C_CLS)     /* 192 zero rows -> exp(0)=1 each */
#define BT 256                     /* batch cols per block */
#define NBT 4                      /* 1024/256 */
#define NBLK (NCT * NBT)           /* 3128 = 8*391, bijective XCD swizzle */

typedef int   i32x4  __attribute__((ext_vector_type(4)));
typedef int   i32x8  __attribute__((ext_vector_type(8)));
typedef float f32x16 __attribute__((ext_vector_type(16)));

// ---- kernel 1: normalize {proto, emb} -> fp8 e4m3; also zero sums/out -------
__global__ void k_norm_all8(const float* __restrict__ emb,
                            const float* __restrict__ proto,
                            unsigned char* __restrict__ ebf8,
                            unsigned char* __restrict__ pbf8,
                            float* __restrict__ sums,
                            float* __restrict__ out) {
  int wid = threadIdx.x >> 6, lane = threadIdx.x & 63;
  int idx = (blockIdx.x << 2) + wid;
  const float* src;
  unsigned char* dst;
  if (idx < CPAD) {
    if (idx >= C_CLS) {
      *reinterpret_cast<unsigned int*>(pbf8 + (size_t)idx * D_DIM + lane * 4) = 0u;
      return;
    }
    src = proto + (size_t)idx * D_DIM;
    dst = pbf8 + (size_t)idx * D_DIM;
  } else {
    int row = idx - CPAD;
    if (lane == 0) sums[row] = 0.0f;          // re-zeroed every call
    if (idx == CPAD && lane == 1) *out = 0.0f;
    src = emb + (size_t)row * D_DIM;
    dst = ebf8 + (size_t)row * D_DIM;
  }
  const float4 v = *reinterpret_cast<const float4*>(src + lane * 4);
  float ss = v.x * v.x + v.y * v.y + v.z * v.z + v.w * v.w;
#pragma unroll
  for (int m = 32; m >= 1; m >>= 1) ss += __shfl_xor(ss, m, 64);
  float inv = 1.0f / fmaxf(sqrtf(ss), 1e-12f);
  int packed = 0;
  packed = __builtin_amdgcn_cvt_pk_fp8_f32(v.x * inv, v.y * inv, packed, false);
  packed = __builtin_amdgcn_cvt_pk_fp8_f32(v.z * inv, v.w * inv, packed, true);
  *reinterpret_cast<int*>(dst + lane * 4) = packed;
}

// ---- kernel 2: swapped MX-fp8 GEMM + in-lane exp-sum (R11 x 2 batch) ---------
// Block = 256 classes x 256 batch cols. Proto tile (64 KB, all K) staged once
// via global_load_lds (pbf8 is L3-hot); 8 waves = 4wc x 2wb, wave tile
// 64c x 128b processed as 4 unrolled strips of 32 cols. Zero barriers in the
// compute path; in-lane exp-sum (class dim is lane-local).
__global__ __launch_bounds__(512, 4) void k_gemm_sw2(
    const unsigned char* __restrict__ ebf8, const unsigned char* __restrict__ pbf8,
    float* __restrict__ sums) {
  __shared__ __align__(16) unsigned char Pls[CT * 256];   // 64 KiB, row = 256 B
  __shared__ float bsum[BT];                              // 1 KiB

  const int t = threadIdx.x;
  const int lane = t & 63;
  const int rsel = lane & 31;       // class-row (A) / batch-col (B) within 32
  const int h = lane >> 5;          // k-half of each 64-K window
  const int wv = t >> 6;
  const int wc = wv >> 1;           // 0..3 : 64-class strip
  const int wb = wv & 1;            // 0..1 : 128-batch strip

  int bid = (int)blockIdx.x;
  int w = (bid & 7) * (NBLK / 8) + (bid >> 3);   // bijective: 3128 = 8*391
  const int ct = w >> 2;                         // 4 bt-blocks share a ct
  const int bt = w & 3;
  const int c0 = ct * CT;
  const int b0 = bt * BT;

  // ---- prologue: stage whole proto tile (256 rows x 256 B), XOR ^(r&15) ----
#pragma unroll
  for (int j = 0; j < 8; ++j) {
    int G = j * 512 + t;            // 16-B granule index, 0..4095
    int r = G >> 4, p = G & 15;
    int lg = p ^ (r & 15);
    const unsigned char* g = pbf8 + (size_t)(c0 + r) * D_DIM + lg * 16;
    __builtin_amdgcn_global_load_lds(
        (const __attribute__((address_space(1))) unsigned int*)(const void*)g,
        (__attribute__((address_space(3))) unsigned int*)(void*)(Pls + G * 16),
        16, 0, 0);
  }
  if (t < BT) bsum[t] = 0.0f;
  asm volatile("s_waitcnt vmcnt(0)" ::: "memory");
  __syncthreads();                   // ONLY barrier before the epilogue

  // ---- 4 unrolled strips of 32 batch cols ----
  const unsigned char* ebase =
      ebf8 + (size_t)(b0 + wb * 128 + rsel) * D_DIM + h * 32;
#pragma unroll
  for (int u = 0; u < 4; ++u) {
    const unsigned char* eb = ebase + (size_t)u * (32 * D_DIM);
    i32x8 bf[4];
#pragma unroll
    for (int ks = 0; ks < 4; ++ks) {
      i32x4 lo = *reinterpret_cast<const i32x4*>(eb + ks * 64);
      i32x4 hi = *reinterpret_cast<const i32x4*>(eb + ks * 64 + 16);
      bf[ks] = __builtin_shufflevector(lo, hi, 0, 1, 2, 3, 4, 5, 6, 7);
    }
    f32x16 acc[2];
#pragma unroll
    for (int mi = 0; mi < 2; ++mi)
#pragma unroll
      for (int e = 0; e < 16; ++e) acc[mi][e] = 0.0f;
#pragma unroll
    for (int ks = 0; ks < 4; ++ks) {
      const int g = ks * 4 + h * 2;
#pragma unroll
      for (int mi = 0; mi < 2; ++mi) {
        int ra = wc * 64 + mi * 32 + rsel;
        int p0 = g ^ (ra & 15), p1 = (g + 1) ^ (ra & 15);
        i32x4 lo = *reinterpret_cast<const i32x4*>(Pls + ra * 256 + p0 * 16);
        i32x4 hi = *reinterpret_cast<const i32x4*>(Pls + ra * 256 + p1 * 16);
        i32x8 af = __builtin_shufflevector(lo, hi, 0, 1, 2, 3, 4, 5, 6, 7);
        acc[mi] = __builtin_amdgcn_mfma_scale_f32_32x32x64_f8f6f4(
            af, bf[ks], acc[mi], 0, 0,          // cbsz=fp8, blgp=fp8
            0, 0x7F7F7F7F, 0, 0x7F7F7F7F);      // unit scales (E8M0=127)
      }
    }
    // in-lane exp-sum over this lane's 32 class cells for col u*32+rsel
    float bp = 0.0f;
#pragma unroll
    for (int mi = 0; mi < 2; ++mi)
#pragma unroll
      for (int e = 0; e < 16; ++e)
        bp += __expf(S_SC * acc[mi][e]);
    bp += __shfl_xor(bp, 32, 64);    // combine the two k-half lane groups
    if (h == 0) atomicAdd(&bsum[wb * 128 + u * 32 + rsel], bp);  // 4-way (wc)
  }

  // ---- block reduce -> global ----
  __syncthreads();
  if (t < BT) atomicAdd(&sums[b0 + t], bsum[t]);
}

// ---------------- kernel 3: label column + final loss -------------------------
__device__ __forceinline__ float f8tof(unsigned char u) {
  int e = (u >> 3) & 15, m = u & 7;
  float mag = e ? ldexpf((float)(8 + m), e - 10) : ldexpf((float)m, -9);
  return (u & 0x80) ? -mag : mag;
}

__global__ void k_finalize(const unsigned char* __restrict__ ebf8,
                           const unsigned char* __restrict__ pbf8,
                           const int* __restrict__ labels,
                           const float* __restrict__ sums,
                           float* __restrict__ out) {
  __shared__ float part[4];
  int wid = threadIdx.x >> 6, lane = threadIdx.x & 63;
  int b = (blockIdx.x << 2) + wid;
  int lab = labels[b];
  const unsigned char* e = ebf8 + (size_t)b * D_DIM + lane * 4;
  const unsigned char* p = pbf8 + (size_t)lab * D_DIM + lane * 4;
  unsigned int eu = *reinterpret_cast<const unsigned int*>(e);
  unsigned int pu = *reinterpret_cast<const unsigned int*>(p);
  float dot = 0.0f;
#pragma unroll
  for (int i = 0; i < 4; ++i)
    dot += f8tof((eu >> (8 * i)) & 0xff) * f8tof((pu >> (8 * i)) & 0xff);
#pragma unroll
  for (int m = 32; m >= 1; m >>= 1) dot += __shfl_xor(dot, m, 64);
  if (lane == 0) {
    float cs = dot;
    float sn = sqrtf(fmaxf(1.0f - cs * cs, EPS_F));
    sn = fminf(fmaxf(sn, EPS_F), 1.0f - EPS_F);
    float phi = cs * COS_M_F - sn * SIN_M_F;
    float sp = S_SC * phi;
    // subtract the 192 zero-pad rows' exp(0)=1 contributions
    float total = sums[b] - (float)NPADROW - __expf(S_SC * cs) + __expf(sp);
    part[wid] = logf(total) - sp;
  }
  __syncthreads();
  if (threadIdx.x == 0) {
    float s = part[0] + part[1] + part[2] + part[3];
    atomicAdd(out, s * (1.0f / (float)B_ROWS));
  }
}

// ---------------- launcher ----------------------------------------------------
extern "C" void kernel_launch(void* const* d_in, const int* in_sizes, int n_in,
                              void* d_out, int out_size, void* d_ws, size_t ws_size,
                              hipStream_t stream) {
  const float* emb    = (const float*)d_in[0];
  const int*   labels = (const int*)d_in[1];
  const float* proto  = (const float*)d_in[2];
  float* out = (float*)d_out;

  char* ws = (char*)d_ws;
  unsigned char* ebf8 = (unsigned char*)ws;                 // 262144 B
  float* sums = (float*)(ws + 262144);                      // 4096 B
  unsigned char* pbf8 = (unsigned char*)(ws + 2097152);     // CPAD*256 = 51.2 MB

  k_norm_all8<<<(CPAD + B_ROWS) / 4, 256, 0, stream>>>(emb, proto, ebf8, pbf8,
                                                       sums, out);
  k_gemm_sw2<<<NBLK, 512, 0, stream>>>(ebf8, pbf8, sums);
  k_finalize<<<B_ROWS / 4, 256, 0, stream>>>(ebf8, pbf8, labels, sums, out);
}